// Round 1
// baseline (1153.710 us; speedup 1.0000x reference)
//
#include <hip/hip_runtime.h>
#include <math.h>

// Problem constants
#define MM     64      // M modes
#define BATCH  1024    // batch
#define D0     64      // input dim
#define WIDTH  256     // hidden width
#define WIN    65      // 2L+1
#define NOUT   4096    // N
#define XILEN  4160    // N + 2L

__device__ __forceinline__ float sigm(float x) {
    return 1.0f / (1.0f + __expf(-x));
}

// u (1024,64) -> uT (64,1024)
__global__ void transpose_u(const float* __restrict__ u, float* __restrict__ uT) {
    __shared__ float tile[32][33];
    int bx = blockIdx.x;           // batch tile (32 of them, 32 wide)
    int by = blockIdx.y;           // d tile (2 of them, 32 wide)
    int tx = threadIdx.x % 32, ty = threadIdx.x / 32;  // 256 thr: ty 0..7
    for (int r = ty; r < 32; r += 8)
        tile[r][tx] = u[(size_t)(bx * 32 + r) * D0 + by * 32 + tx];
    __syncthreads();
    for (int r = ty; r < 32; r += 8)
        uT[(size_t)(by * 32 + r) * BATCH + bx * 32 + tx] = tile[tx][r];
}

// Y[m] (R x 1024) = sigmoid( W[m] (R x K) @ X[m] (K x 1024) + bias[m] )
// grid: (BATCH/64, ceil(R/64), MM), block: 256
__global__ void mlp_gemm(const float* __restrict__ W, const float* __restrict__ bias,
                         const float* __restrict__ X, float* __restrict__ Y,
                         int R, int K, int x_m_stride) {
    const int m  = blockIdx.z;
    const int r0 = blockIdx.y * 64;
    const int b0 = blockIdx.x * 64;
    const float* Wm = W + (size_t)m * R * K;
    const float* Xm = X + (size_t)m * x_m_stride;
    float*       Ym = Y + (size_t)m * R * BATCH;
    const float* bm = bias + (size_t)m * R;

    __shared__ float Ws[16][72];   // [kk][row] (transposed W tile), 288B rows, 16B aligned
    __shared__ float Xs[16][68];   // [kk][col], 272B rows, 16B aligned

    const int tid = threadIdx.x;
    const int tx = tid % 16, ty = tid / 16;
    float acc[4][4] = {};

    for (int k0 = 0; k0 < K; k0 += 16) {
        // W tile: 64 rows x 16 k -> Ws[kk][row]
        for (int i = tid; i < 64 * 16; i += 256) {
            int kk = i % 16, rr = i / 16;
            int r = r0 + rr;
            Ws[kk][rr] = (r < R) ? Wm[(size_t)r * K + (k0 + kk)] : 0.0f;
        }
        // X tile: 16 k x 64 cols -> Xs[kk][col]  (coalesced over col)
        for (int i = tid; i < 16 * 64; i += 256) {
            int cc = i % 64, kk = i / 64;
            Xs[kk][cc] = Xm[(size_t)(k0 + kk) * BATCH + (b0 + cc)];
        }
        __syncthreads();
        #pragma unroll
        for (int kk = 0; kk < 16; ++kk) {
            float4 av = *(const float4*)&Ws[kk][ty * 4];
            float4 bv = *(const float4*)&Xs[kk][tx * 4];
            const float a[4] = {av.x, av.y, av.z, av.w};
            const float b[4] = {bv.x, bv.y, bv.z, bv.w};
            #pragma unroll
            for (int ii = 0; ii < 4; ++ii)
                #pragma unroll
                for (int jj = 0; jj < 4; ++jj)
                    acc[ii][jj] += a[ii] * b[jj];
        }
        __syncthreads();
    }

    #pragma unroll
    for (int ii = 0; ii < 4; ++ii) {
        int r = r0 + ty * 4 + ii;
        if (r < R) {
            float bv = bm[r];
            float4 o;
            o.x = sigm(acc[ii][0] + bv);
            o.y = sigm(acc[ii][1] + bv);
            o.z = sigm(acc[ii][2] + bv);
            o.w = sigm(acc[ii][3] + bv);
            *(float4*)&Ym[(size_t)r * BATCH + b0 + tx * 4] = o;
        }
    }
}

// out[n,b] = sum_m sum_j xi[m, n+j] * G[m, j, b]
// grid: (BATCH/64, NOUT/64), block: 256
__global__ void contract_out(const float* __restrict__ xi, const float* __restrict__ G,
                             float* __restrict__ out) {
    const int b0 = blockIdx.x * 64;
    const int n0 = blockIdx.y * 64;
    const int tid = threadIdx.x;
    const int tx = tid % 16, ty = tid / 16;

    __shared__ float xs[128];       // xi[m, n0 .. n0+127]
    __shared__ float Gs[WIN][68];   // [j][col]

    float acc[4][4] = {};

    for (int m = 0; m < MM; ++m) {
        if (tid < 128) xs[tid] = xi[(size_t)m * XILEN + n0 + tid];
        for (int i = tid; i < WIN * 64; i += 256) {
            int bl = i % 64, j = i / 64;
            Gs[j][bl] = G[((size_t)m * WIN + j) * BATCH + b0 + bl];
        }
        __syncthreads();
        #pragma unroll 5
        for (int j = 0; j < WIN; ++j) {
            float a[4];
            #pragma unroll
            for (int ii = 0; ii < 4; ++ii) a[ii] = xs[ty * 4 + ii + j];
            float4 bv = *(const float4*)&Gs[j][tx * 4];
            const float b[4] = {bv.x, bv.y, bv.z, bv.w};
            #pragma unroll
            for (int ii = 0; ii < 4; ++ii)
                #pragma unroll
                for (int jj = 0; jj < 4; ++jj)
                    acc[ii][jj] += a[ii] * b[jj];
        }
        __syncthreads();
    }

    #pragma unroll
    for (int ii = 0; ii < 4; ++ii) {
        int n = n0 + ty * 4 + ii;
        float4 o = {acc[ii][0], acc[ii][1], acc[ii][2], acc[ii][3]};
        *(float4*)&out[(size_t)n * BATCH + b0 + tx * 4] = o;
    }
}

extern "C" void kernel_launch(void* const* d_in, const int* in_sizes, int n_in,
                              void* d_out, int out_size, void* d_ws, size_t ws_size,
                              hipStream_t stream) {
    const float* u    = (const float*)d_in[0];   // (1024, 64)
    const float* w0   = (const float*)d_in[1];   // (64, 256, 64)
    const float* b0_  = (const float*)d_in[2];   // (64, 256, 1)
    const float* w    = (const float*)d_in[3];   // (3, 64, 256, 256)
    const float* b    = (const float*)d_in[4];   // (3, 64, 256, 1)
    const float* wf   = (const float*)d_in[5];   // (64, 65, 256)
    const float* bf   = (const float*)d_in[6];   // (64, 65, 1)
    const float* xi   = (const float*)d_in[7];   // (64, 4160)
    float* out = (float*)d_out;                  // (4096, 1024)

    float* ws   = (float*)d_ws;
    float* uT   = ws;                                   // 64*1024
    float* bufA = uT + (size_t)D0 * BATCH;              // 64*256*1024
    float* bufB = bufA + (size_t)MM * WIDTH * BATCH;    // 64*256*1024
    float* G    = bufB + (size_t)MM * WIDTH * BATCH;    // 64*65*1024

    const size_t wstride = (size_t)MM * WIDTH * WIDTH;  // per-layer weight stride
    const size_t bstride = (size_t)MM * WIDTH;          // per-layer bias stride
    const int    xms     = WIDTH * BATCH;               // X per-m stride (hidden/final)

    transpose_u<<<dim3(32, 2), 256, 0, stream>>>(u, uT);

    // layer 0: R=256, K=64, X = uT shared across m (stride 0)
    mlp_gemm<<<dim3(16, 4, MM), 256, 0, stream>>>(w0, b0_, uT, bufA, WIDTH, D0, 0);

    // hidden layers 1..3
    mlp_gemm<<<dim3(16, 4, MM), 256, 0, stream>>>(w + 0 * wstride, b + 0 * bstride,
                                                  bufA, bufB, WIDTH, WIDTH, xms);
    mlp_gemm<<<dim3(16, 4, MM), 256, 0, stream>>>(w + 1 * wstride, b + 1 * bstride,
                                                  bufB, bufA, WIDTH, WIDTH, xms);
    mlp_gemm<<<dim3(16, 4, MM), 256, 0, stream>>>(w + 2 * wstride, b + 2 * bstride,
                                                  bufA, bufB, WIDTH, WIDTH, xms);

    // final layer: R=65, K=256 -> G (64, 65, 1024)
    mlp_gemm<<<dim3(16, 2, MM), 256, 0, stream>>>(wf, bf, bufB, G, WIN, WIDTH, xms);

    // windowed contraction -> out (4096, 1024)
    contract_out<<<dim3(BATCH / 64, NOUT / 64), 256, 0, stream>>>(xi, G, out);
}

// Round 2
// 383.673 us; speedup vs baseline: 3.0070x; 3.0070x over previous
//
#include <hip/hip_runtime.h>
#include <math.h>

#define BK 64

typedef __attribute__((ext_vector_type(8))) short short8;
typedef __attribute__((ext_vector_type(4))) float floatx4;
typedef __attribute__((ext_vector_type(4))) unsigned short ushort4v;

__device__ __forceinline__ void load_lds16(const void* g, void* l) {
    __builtin_amdgcn_global_load_lds((const __attribute__((address_space(1))) void*)g,
                                     (__attribute__((address_space(3))) void*)l,
                                     16, 0, 0);
}

__device__ __forceinline__ unsigned short f2bf(float x) {
    union { float f; unsigned int u; } v; v.f = x;
    unsigned int r = v.u + 0x7fffu + ((v.u >> 16) & 1u);
    return (unsigned short)(r >> 16);
}

__device__ __forceinline__ float sigm(float x) { return 1.0f / (1.0f + __expf(-x)); }

// ---- fp32 -> bf16 elementwise (n4 = n/4) ----
__global__ void cvt_bf16(const float* __restrict__ src, unsigned short* __restrict__ dst, int n4) {
    int i = blockIdx.x * 256 + threadIdx.x;
    if (i >= n4) return;
    float4 v = ((const float4*)src)[i];
    ushort4v o = { f2bf(v.x), f2bf(v.y), f2bf(v.z), f2bf(v.w) };
    ((ushort4v*)dst)[i] = o;
}

// ---- weight_final (64,65,256) fp32 -> (64,128,256) bf16 zero-padded rows ----
__global__ void cvt_wf(const float* __restrict__ wf, unsigned short* __restrict__ dst) {
    int idx = blockIdx.x * 256 + threadIdx.x;   // per 4 elements, total 64*128*256/4
    int e = idx * 4;
    int m = e >> 15;           // / (128*256)
    int r = (e >> 8) & 127;
    int c = e & 255;
    ushort4v o = {0, 0, 0, 0};
    if (r < 65) {
        float4 v = *(const float4*)&wf[((size_t)m * 65 + r) * 256 + c];
        o = (ushort4v){ f2bf(v.x), f2bf(v.y), f2bf(v.z), f2bf(v.w) };
    }
    ((ushort4v*)dst)[idx] = o;
}

// ---- Toeplitz build: XW[n][m*68+j] = bf16(xi[m][n+j]) for j<65 else 0 ----
// grid (32 n-chunks of 128, 64 m), block 256
__global__ void build_xw(const float* __restrict__ xi, unsigned int* __restrict__ xw) {
    const int m = blockIdx.y;
    const int n0 = blockIdx.x * 128;
    const float* xim = xi + (size_t)m * 4160;
    for (int t = 0; t < 17; ++t) {
        const int d = threadIdx.x * 17 + t;     // 0..4351 dwords = 128 rows x 34
        const int row = d / 34;
        const int pos = d - row * 34;
        const int n = n0 + row;
        const int j0 = pos * 2;
        const float v0 = (j0 < 65) ? xim[n + j0] : 0.0f;
        const float v1 = (j0 + 1 < 65) ? xim[n + j0 + 1] : 0.0f;
        const unsigned int p = (unsigned int)f2bf(v0) | ((unsigned int)f2bf(v1) << 16);
        xw[(size_t)n * 2176 + (size_t)m * 34 + pos] = p;
    }
}

// ---- Generic MFMA GEMM: D[r][c] = sum_k A[r][k] * B[c][k]  (both bf16, k-contiguous)
// EPI==0: Y[c][r] = bf16(sigmoid(D + bias[r]))   (transposed bf16 store)
// EPI==1: out[r][c] = D (fp32 store)
// grid: (C/128, Rpad/128, M); block 256 = 4 waves; tile 128x128; BK=64.
template<int EPI>
__global__ __launch_bounds__(256, 2)
void gemm_bf16(const unsigned short* __restrict__ A, long long sA, int lda,
               const unsigned short* __restrict__ B, long long sB, int ldb,
               const float* __restrict__ bias, int sbias, int Rbias,
               void* __restrict__ Yv, long long sY, int ldy, int Rstore,
               int K) {
    const int m = blockIdx.z;
    const unsigned short* Am = A + (size_t)m * sA;
    const unsigned short* Bm = B + (size_t)m * sB;

    __shared__ unsigned short As[128 * 64];
    __shared__ unsigned short Bs[128 * 64];

    const int tid  = threadIdx.x;
    const int wave = tid >> 6;
    const int lane = tid & 63;
    const int quad = lane >> 4;
    const int l16  = lane & 15;
    const int r0 = blockIdx.y * 128;
    const int c0 = blockIdx.x * 128;
    const int wr = (wave & 1) * 64;
    const int wc = (wave >> 1) * 64;

    // staging geometry: per wave-instr, 8 rows x 8 chunks of 16B (lane = row*8+pos)
    const int srow = wave * 32 + (lane >> 3);
    const int spos = lane & 7;

    floatx4 acc[4][4];
    const floatx4 zero = {0.f, 0.f, 0.f, 0.f};
    #pragma unroll
    for (int i = 0; i < 4; ++i)
        #pragma unroll
        for (int j = 0; j < 4; ++j) acc[i][j] = zero;

    for (int k0 = 0; k0 < K; k0 += BK) {
        #pragma unroll
        for (int t = 0; t < 4; ++t) {
            const int row = srow + t * 8;          // LDS-local row 0..127
            const int fc  = spos ^ (row & 7);      // XOR-swizzled chunk to fetch
            load_lds16(Am + (size_t)(r0 + row) * lda + k0 + fc * 8,
                       &As[(wave * 32 + t * 8) * 64]);
            load_lds16(Bm + (size_t)(c0 + row) * ldb + k0 + fc * 8,
                       &Bs[(wave * 32 + t * 8) * 64]);
        }
        __syncthreads();

        #pragma unroll
        for (int kk = 0; kk < 2; ++kk) {
            short8 af[4], bfr[4];
            #pragma unroll
            for (int i = 0; i < 4; ++i) {
                const int ra = wr + i * 16 + l16;
                af[i]  = *(const short8*)&As[ra * 64 + (((kk * 4 + quad) ^ (ra & 7)) * 8)];
                const int cb = wc + i * 16 + l16;
                bfr[i] = *(const short8*)&Bs[cb * 64 + (((kk * 4 + quad) ^ (cb & 7)) * 8)];
            }
            #pragma unroll
            for (int i = 0; i < 4; ++i)
                #pragma unroll
                for (int j = 0; j < 4; ++j)
                    acc[i][j] = __builtin_amdgcn_mfma_f32_16x16x32_bf16(af[i], bfr[j], acc[i][j], 0, 0, 0);
        }
        __syncthreads();
    }

    if (EPI == 0) {
        unsigned short* Ym = (unsigned short*)Yv + (size_t)m * sY;
        const float* bm = bias + (size_t)m * sbias;
        #pragma unroll
        for (int i = 0; i < 4; ++i) {
            const int rbase = r0 + wr + i * 16 + quad * 4;
            if (rbase < Rstore) {
                float bv[4];
                #pragma unroll
                for (int rr = 0; rr < 4; ++rr)
                    bv[rr] = (rbase + rr < Rbias) ? bm[rbase + rr] : 0.0f;
                #pragma unroll
                for (int j = 0; j < 4; ++j) {
                    const int col = c0 + wc + j * 16 + l16;
                    ushort4v o;
                    #pragma unroll
                    for (int rr = 0; rr < 4; ++rr)
                        o[rr] = f2bf(sigm(acc[i][j][rr] + bv[rr]));
                    *(ushort4v*)&Ym[(size_t)col * ldy + rbase] = o;
                }
            }
        }
    } else {
        float* O = (float*)Yv;
        #pragma unroll
        for (int i = 0; i < 4; ++i) {
            const int rb = r0 + wr + i * 16 + quad * 4;
            #pragma unroll
            for (int rr = 0; rr < 4; ++rr) {
                #pragma unroll
                for (int j = 0; j < 4; ++j) {
                    const int col = c0 + wc + j * 16 + l16;
                    O[(size_t)(rb + rr) * ldy + col] = acc[i][j][rr];
                }
            }
        }
    }
}

extern "C" void kernel_launch(void* const* d_in, const int* in_sizes, int n_in,
                              void* d_out, int out_size, void* d_ws, size_t ws_size,
                              hipStream_t stream) {
    const float* u   = (const float*)d_in[0];   // (1024, 64)
    const float* w0  = (const float*)d_in[1];   // (64, 256, 64)
    const float* b0_ = (const float*)d_in[2];   // (64, 256)
    const float* w   = (const float*)d_in[3];   // (3, 64, 256, 256)
    const float* b   = (const float*)d_in[4];   // (3, 64, 256)
    const float* wf  = (const float*)d_in[5];   // (64, 65, 256)
    const float* bf_ = (const float*)d_in[6];   // (64, 65)
    const float* xi  = (const float*)d_in[7];   // (64, 4160)
    float* out = (float*)d_out;                 // (4096, 1024)

    unsigned short* u_bf  = (unsigned short*)d_ws;                 // 65,536
    unsigned short* w0_bf = u_bf  + 65536;                         // 1,048,576
    unsigned short* w_bf  = w0_bf + 1048576;                       // 12,582,912
    unsigned short* wf_bf = w_bf  + 12582912;                      // 2,097,152 (64x128x256, padded)
    unsigned short* bufA  = wf_bf + 2097152;                       // 16,777,216 (64x1024x256)
    unsigned short* bufB  = bufA  + 16777216;                      // 16,777,216
    unsigned short* Gflat = bufB  + 16777216;                      // 4,456,448 (1024x4352)
    unsigned short* XW    = Gflat + 4456448;                       // 17,825,792 (4096x4352)

    // conversions
    cvt_bf16<<<64,    256, 0, stream>>>(u,  u_bf,  65536 / 4);
    cvt_bf16<<<1024,  256, 0, stream>>>(w0, w0_bf, 1048576 / 4);
    cvt_bf16<<<12288, 256, 0, stream>>>(w,  w_bf,  12582912 / 4);
    cvt_wf  <<<2048,  256, 0, stream>>>(wf, wf_bf);
    build_xw<<<dim3(32, 64), 256, 0, stream>>>(xi, (unsigned int*)XW);

    // layer 0: (256x64) @ u[b][d] -> bufA[b][w]
    gemm_bf16<0><<<dim3(8, 2, 64), 256, 0, stream>>>(
        w0_bf, 256 * 64, 64, u_bf, 0, 64,
        b0_, 256, 256, bufA, 1024 * 256, 256, 256, 64);

    // hidden layers: ping-pong bufA <-> bufB
    gemm_bf16<0><<<dim3(8, 2, 64), 256, 0, stream>>>(
        w_bf + 0LL * 64 * 256 * 256, 256 * 256, 256, bufA, 1024 * 256, 256,
        b + 0LL * 64 * 256, 256, 256, bufB, 1024 * 256, 256, 256, 256);
    gemm_bf16<0><<<dim3(8, 2, 64), 256, 0, stream>>>(
        w_bf + 1LL * 64 * 256 * 256, 256 * 256, 256, bufB, 1024 * 256, 256,
        b + 1LL * 64 * 256, 256, 256, bufA, 1024 * 256, 256, 256, 256);
    gemm_bf16<0><<<dim3(8, 2, 64), 256, 0, stream>>>(
        w_bf + 2LL * 64 * 256 * 256, 256 * 256, 256, bufA, 1024 * 256, 256,
        b + 2LL * 64 * 256, 256, 256, bufB, 1024 * 256, 256, 256, 256);

    // final layer: (68x256 padded to 128) @ bufB -> Gflat[b][m*68 + j]
    gemm_bf16<0><<<dim3(8, 1, 64), 256, 0, stream>>>(
        wf_bf, 128 * 256, 256, bufB, 1024 * 256, 256,
        bf_, 65, 65, Gflat, 68, 4352, 68, 256);

    // contraction: out[n][b] = XW[n][:] . Gflat[b][:]   (K = 4352)
    gemm_bf16<1><<<dim3(8, 32, 1), 256, 0, stream>>>(
        XW, 0, 4352, Gflat, 0, 4352,
        nullptr, 0, 0, out, 0, 1024, 1 << 30, 4352);
}

// Round 3
// 362.938 us; speedup vs baseline: 3.1788x; 1.0571x over previous
//
#include <hip/hip_runtime.h>
#include <math.h>

#define BK 64

typedef __attribute__((ext_vector_type(8))) short short8;
typedef __attribute__((ext_vector_type(4))) float floatx4;
typedef __attribute__((ext_vector_type(4))) unsigned short ushort4v;

__device__ __forceinline__ void load_lds16(const void* g, void* l) {
    __builtin_amdgcn_global_load_lds((const __attribute__((address_space(1))) void*)g,
                                     (__attribute__((address_space(3))) void*)l,
                                     16, 0, 0);
}

__device__ __forceinline__ unsigned short f2bf(float x) {
    union { float f; unsigned int u; } v; v.f = x;
    unsigned int r = v.u + 0x7fffu + ((v.u >> 16) & 1u);
    return (unsigned short)(r >> 16);
}

__device__ __forceinline__ float sigm(float x) { return 1.0f / (1.0f + __expf(-x)); }

// ---- fp32 -> bf16 elementwise (n4 = n/4) ----
__global__ void cvt_bf16(const float* __restrict__ src, unsigned short* __restrict__ dst, int n4) {
    int i = blockIdx.x * 256 + threadIdx.x;
    if (i >= n4) return;
    float4 v = ((const float4*)src)[i];
    ushort4v o = { f2bf(v.x), f2bf(v.y), f2bf(v.z), f2bf(v.w) };
    ((ushort4v*)dst)[i] = o;
}

// ---- weight_final (64,65,256) fp32 -> (64,128,256) bf16 zero-padded rows ----
__global__ void cvt_wf(const float* __restrict__ wf, unsigned short* __restrict__ dst) {
    int idx = blockIdx.x * 256 + threadIdx.x;
    int e = idx * 4;
    int m = e >> 15;
    int r = (e >> 8) & 127;
    int c = e & 255;
    ushort4v o = {0, 0, 0, 0};
    if (r < 65) {
        float4 v = *(const float4*)&wf[((size_t)m * 65 + r) * 256 + c];
        o = (ushort4v){ f2bf(v.x), f2bf(v.y), f2bf(v.z), f2bf(v.w) };
    }
    ((ushort4v*)dst)[idx] = o;
}

// ---- Toeplitz build: XW[n][m*68+j] = bf16(xi[m][n+j]) for j<65 else 0 ----
__global__ void build_xw(const float* __restrict__ xi, unsigned int* __restrict__ xw) {
    const int m = blockIdx.y;
    const int n0 = blockIdx.x * 128;
    const float* xim = xi + (size_t)m * 4160;
    for (int t = 0; t < 17; ++t) {
        const int d = threadIdx.x * 17 + t;
        const int row = d / 34;
        const int pos = d - row * 34;
        const int n = n0 + row;
        const int j0 = pos * 2;
        const float v0 = (j0 < 65) ? xim[n + j0] : 0.0f;
        const float v1 = (j0 + 1 < 65) ? xim[n + j0 + 1] : 0.0f;
        const unsigned int p = (unsigned int)f2bf(v0) | ((unsigned int)f2bf(v1) << 16);
        xw[(size_t)n * 2176 + (size_t)m * 34 + pos] = p;
    }
}

// ---- MLP MFMA GEMM: Y[c][r] = bf16(sigmoid(sum_k A[r][k]B[c][k] + bias[r]))
// 1-D grid = 8*rtiles*64 blocks; XCD swizzle: same-m blocks colocate per XCD.
// bpm_shift = log2(8*rtiles).
__global__ __launch_bounds__(256, 2)
void gemm_bf16(const unsigned short* __restrict__ A, long long sA, int lda,
               const unsigned short* __restrict__ B, long long sB, int ldb,
               const float* __restrict__ bias, int sbias, int Rbias,
               unsigned short* __restrict__ Y, long long sY, int ldy, int Rstore,
               int K, int bpm_shift) {
    const int bid  = blockIdx.x;
    const int xcd  = bid & 7;
    const int slot = bid >> 3;
    const int m    = (xcd << 3) + (slot >> bpm_shift);
    const int w    = slot & ((1 << bpm_shift) - 1);
    const int c0 = (w & 7) << 7;
    const int r0 = (w >> 3) << 7;

    const unsigned short* Am = A + (size_t)m * sA;
    const unsigned short* Bm = B + (size_t)m * sB;

    __shared__ unsigned short As[128 * 64];
    __shared__ unsigned short Bs[128 * 64];

    const int tid  = threadIdx.x;
    const int wave = tid >> 6;
    const int lane = tid & 63;
    const int quad = lane >> 4;
    const int l16  = lane & 15;
    const int wr = (wave & 1) * 64;
    const int wc = (wave >> 1) * 64;

    const int srow = wave * 32 + (lane >> 3);
    const int spos = lane & 7;

    floatx4 acc[4][4];
    const floatx4 zero = {0.f, 0.f, 0.f, 0.f};
    #pragma unroll
    for (int i = 0; i < 4; ++i)
        #pragma unroll
        for (int j = 0; j < 4; ++j) acc[i][j] = zero;

    for (int k0 = 0; k0 < K; k0 += BK) {
        #pragma unroll
        for (int t = 0; t < 4; ++t) {
            const int row = srow + t * 8;
            const int fc  = spos ^ (row & 7);
            load_lds16(Am + (size_t)(r0 + row) * lda + k0 + fc * 8,
                       &As[(wave * 32 + t * 8) * 64]);
            load_lds16(Bm + (size_t)(c0 + row) * ldb + k0 + fc * 8,
                       &Bs[(wave * 32 + t * 8) * 64]);
        }
        __syncthreads();

        #pragma unroll
        for (int kk = 0; kk < 2; ++kk) {
            short8 af[4], bfr[4];
            #pragma unroll
            for (int i = 0; i < 4; ++i) {
                const int ra = wr + i * 16 + l16;
                af[i]  = *(const short8*)&As[ra * 64 + (((kk * 4 + quad) ^ (ra & 7)) * 8)];
                const int cb = wc + i * 16 + l16;
                bfr[i] = *(const short8*)&Bs[cb * 64 + (((kk * 4 + quad) ^ (cb & 7)) * 8)];
            }
            #pragma unroll
            for (int i = 0; i < 4; ++i)
                #pragma unroll
                for (int j = 0; j < 4; ++j)
                    acc[i][j] = __builtin_amdgcn_mfma_f32_16x16x32_bf16(af[i], bfr[j], acc[i][j], 0, 0, 0);
        }
        __syncthreads();
    }

    const float* bm = bias + (size_t)m * sbias;
    unsigned short* Ym = Y + (size_t)m * sY;
    #pragma unroll
    for (int i = 0; i < 4; ++i) {
        const int rbase = r0 + wr + i * 16 + quad * 4;
        if (rbase < Rstore) {
            float bv[4];
            #pragma unroll
            for (int rr = 0; rr < 4; ++rr)
                bv[rr] = (rbase + rr < Rbias) ? bm[rbase + rr] : 0.0f;
            #pragma unroll
            for (int j = 0; j < 4; ++j) {
                const int col = c0 + wc + j * 16 + l16;
                ushort4v o;
                #pragma unroll
                for (int rr = 0; rr < 4; ++rr)
                    o[rr] = f2bf(sigm(acc[i][j][rr] + bv[rr]));
                *(ushort4v*)&Ym[(size_t)col * ldy + rbase] = o;
            }
        }
    }
}

// ---- Contraction GEMM: out[n][b] = XW[n][:].Gflat[b][:], K=4352, fp32 out.
// 512 threads = 8 waves, wave tile 64x32. Grid 256 1-D with XCD swizzle:
// each n-tile's 8 b-blocks share an XCD (XW tile lives in that L2).
__global__ __launch_bounds__(512, 2)
void contract_gemm(const unsigned short* __restrict__ XW,
                   const unsigned short* __restrict__ G,
                   float* __restrict__ out) {
    const int bid  = blockIdx.x;
    const int xcd  = bid & 7;
    const int slot = bid >> 3;              // 0..31
    const int r0 = ((xcd << 2) + (slot >> 3)) << 7;   // n-tile
    const int c0 = (slot & 7) << 7;                   // b-tile

    __shared__ unsigned short As[128 * 64];
    __shared__ unsigned short Bs[128 * 64];

    const int tid  = threadIdx.x;
    const int wave = tid >> 6;              // 0..7
    const int lane = tid & 63;
    const int quad = lane >> 4;
    const int l16  = lane & 15;
    const int wr = (wave & 1) * 64;
    const int wc = (wave >> 1) * 32;

    const int srow = wave * 16 + (lane >> 3);
    const int spos = lane & 7;

    floatx4 acc[4][2];
    const floatx4 zero = {0.f, 0.f, 0.f, 0.f};
    #pragma unroll
    for (int i = 0; i < 4; ++i)
        #pragma unroll
        for (int j = 0; j < 2; ++j) acc[i][j] = zero;

    for (int k0 = 0; k0 < 4352; k0 += BK) {
        #pragma unroll
        for (int t = 0; t < 2; ++t) {
            const int row = srow + t * 8;
            const int fc  = spos ^ (row & 7);
            load_lds16(XW + (size_t)(r0 + row) * 4352 + k0 + fc * 8,
                       &As[(wave * 16 + t * 8) * 64]);
            load_lds16(G + (size_t)(c0 + row) * 4352 + k0 + fc * 8,
                       &Bs[(wave * 16 + t * 8) * 64]);
        }
        __syncthreads();

        #pragma unroll
        for (int kk = 0; kk < 2; ++kk) {
            short8 af[4], bfr[2];
            #pragma unroll
            for (int i = 0; i < 4; ++i) {
                const int ra = wr + i * 16 + l16;
                af[i] = *(const short8*)&As[ra * 64 + (((kk * 4 + quad) ^ (ra & 7)) * 8)];
            }
            #pragma unroll
            for (int j = 0; j < 2; ++j) {
                const int cb = wc + j * 16 + l16;
                bfr[j] = *(const short8*)&Bs[cb * 64 + (((kk * 4 + quad) ^ (cb & 7)) * 8)];
            }
            #pragma unroll
            for (int i = 0; i < 4; ++i)
                #pragma unroll
                for (int j = 0; j < 2; ++j)
                    acc[i][j] = __builtin_amdgcn_mfma_f32_16x16x32_bf16(af[i], bfr[j], acc[i][j], 0, 0, 0);
        }
        __syncthreads();
    }

    #pragma unroll
    for (int i = 0; i < 4; ++i) {
        const int rb = r0 + wr + i * 16 + quad * 4;
        #pragma unroll
        for (int rr = 0; rr < 4; ++rr) {
            #pragma unroll
            for (int j = 0; j < 2; ++j) {
                const int col = c0 + wc + j * 16 + l16;
                out[(size_t)(rb + rr) * 1024 + col] = acc[i][j][rr];
            }
        }
    }
}

extern "C" void kernel_launch(void* const* d_in, const int* in_sizes, int n_in,
                              void* d_out, int out_size, void* d_ws, size_t ws_size,
                              hipStream_t stream) {
    const float* u   = (const float*)d_in[0];
    const float* w0  = (const float*)d_in[1];
    const float* b0_ = (const float*)d_in[2];
    const float* w   = (const float*)d_in[3];
    const float* b   = (const float*)d_in[4];
    const float* wf  = (const float*)d_in[5];
    const float* bf_ = (const float*)d_in[6];
    const float* xi  = (const float*)d_in[7];
    float* out = (float*)d_out;

    unsigned short* u_bf  = (unsigned short*)d_ws;
    unsigned short* w0_bf = u_bf  + 65536;
    unsigned short* w_bf  = w0_bf + 1048576;
    unsigned short* wf_bf = w_bf  + 12582912;
    unsigned short* bufA  = wf_bf + 2097152;
    unsigned short* bufB  = bufA  + 16777216;
    unsigned short* Gflat = bufB  + 16777216;
    unsigned short* XW    = Gflat + 4456448;

    cvt_bf16<<<64,    256, 0, stream>>>(u,  u_bf,  65536 / 4);
    cvt_bf16<<<1024,  256, 0, stream>>>(w0, w0_bf, 1048576 / 4);
    cvt_bf16<<<12288, 256, 0, stream>>>(w,  w_bf,  12582912 / 4);
    cvt_wf  <<<2048,  256, 0, stream>>>(wf, wf_bf);
    build_xw<<<dim3(32, 64), 256, 0, stream>>>(xi, (unsigned int*)XW);

    // layer 0: rtiles=2 -> bpm_shift=4, grid 1024
    gemm_bf16<<<1024, 256, 0, stream>>>(
        w0_bf, 256 * 64, 64, u_bf, 0, 64,
        b0_, 256, 256, bufA, 1024 * 256, 256, 256, 64, 4);

    // hidden layers
    gemm_bf16<<<1024, 256, 0, stream>>>(
        w_bf + 0LL * 64 * 256 * 256, 256 * 256, 256, bufA, 1024 * 256, 256,
        b + 0LL * 64 * 256, 256, 256, bufB, 1024 * 256, 256, 256, 256, 4);
    gemm_bf16<<<1024, 256, 0, stream>>>(
        w_bf + 1LL * 64 * 256 * 256, 256 * 256, 256, bufB, 1024 * 256, 256,
        b + 1LL * 64 * 256, 256, 256, bufA, 1024 * 256, 256, 256, 256, 4);
    gemm_bf16<<<1024, 256, 0, stream>>>(
        w_bf + 2LL * 64 * 256 * 256, 256 * 256, 256, bufA, 1024 * 256, 256,
        b + 2LL * 64 * 256, 256, 256, bufB, 1024 * 256, 256, 256, 256, 4);

    // final layer: rtiles=1 -> bpm_shift=3, grid 512
    gemm_bf16<<<512, 256, 0, stream>>>(
        wf_bf, 128 * 256, 256, bufB, 1024 * 256, 256,
        bf_, 65, 65, Gflat, 68, 4352, 68, 256, 3);

    // contraction
    contract_gemm<<<256, 512, 0, stream>>>(XW, Gflat, out);
}

// Round 4
// 309.800 us; speedup vs baseline: 3.7240x; 1.1715x over previous
//
#include <hip/hip_runtime.h>
#include <math.h>

#define BK 64

typedef __attribute__((ext_vector_type(8))) short short8;
typedef __attribute__((ext_vector_type(4))) float floatx4;
typedef __attribute__((ext_vector_type(4))) unsigned short ushort4v;

__device__ __forceinline__ void load_lds16(const void* g, void* l) {
    __builtin_amdgcn_global_load_lds((const __attribute__((address_space(1))) void*)g,
                                     (__attribute__((address_space(3))) void*)l,
                                     16, 0, 0);
}

__device__ __forceinline__ unsigned short f2bf(float x) {
    union { float f; unsigned int u; } v; v.f = x;
    unsigned int r = v.u + 0x7fffu + ((v.u >> 16) & 1u);
    return (unsigned short)(r >> 16);
}

__device__ __forceinline__ float sigm(float x) { return 1.0f / (1.0f + __expf(-x)); }

// ---- fused weight conversion: w0 (1024 blk) | w (12288 blk) | wf pad (2048 blk) ----
__global__ void cvt_all(const float* __restrict__ w0, const float* __restrict__ w,
                        const float* __restrict__ wf,
                        unsigned short* __restrict__ w0d, unsigned short* __restrict__ wd,
                        unsigned short* __restrict__ wfd) {
    const int bid = blockIdx.x;
    if (bid < 1024) {
        int i = bid * 256 + threadIdx.x;              // 262144 float4s
        float4 v = ((const float4*)w0)[i];
        ushort4v o = { f2bf(v.x), f2bf(v.y), f2bf(v.z), f2bf(v.w) };
        ((ushort4v*)w0d)[i] = o;
    } else if (bid < 13312) {
        int i = (bid - 1024) * 256 + threadIdx.x;     // 3145728 float4s
        float4 v = ((const float4*)w)[i];
        ushort4v o = { f2bf(v.x), f2bf(v.y), f2bf(v.z), f2bf(v.w) };
        ((ushort4v*)wd)[i] = o;
    } else {
        int idx = (bid - 13312) * 256 + threadIdx.x;  // 524288 chunks of 4
        int e = idx * 4;
        int m = e >> 15;
        int r = (e >> 8) & 127;
        int c = e & 255;
        ushort4v o = {0, 0, 0, 0};
        if (r < 65) {
            float4 v = *(const float4*)&wf[((size_t)m * 65 + r) * 256 + c];
            o = (ushort4v){ f2bf(v.x), f2bf(v.y), f2bf(v.z), f2bf(v.w) };
        }
        ((ushort4v*)wfd)[idx] = o;
    }
}

// ---- Toeplitz build: XW[n][m*68+j] = bf16(xi[m][n+j]) for j<65 else 0 ----
__global__ void build_xw(const float* __restrict__ xi, unsigned int* __restrict__ xw) {
    const int m = blockIdx.y;
    const int n0 = blockIdx.x * 128;
    const float* xim = xi + (size_t)m * 4160;
    for (int t = 0; t < 17; ++t) {
        const int d = threadIdx.x * 17 + t;
        const int row = d / 34;
        const int pos = d - row * 34;
        const int n = n0 + row;
        const int j0 = pos * 2;
        const float v0 = (j0 < 65) ? xim[n + j0] : 0.0f;
        const float v1 = (j0 + 1 < 65) ? xim[n + j0 + 1] : 0.0f;
        const unsigned int p = (unsigned int)f2bf(v0) | ((unsigned int)f2bf(v1) << 16);
        xw[(size_t)n * 2176 + (size_t)m * 34 + pos] = p;
    }
}

// ---- one MLP layer inside the fused kernel ----
// A (weights) read straight from global (L2-hot); B (activations) from LDS.
// X layout in LDS: X[b][k] at b*256 + ((k/8) ^ (b&7))*8 + (k&7)   (shorts)
template<int K, int I, bool FINAL>
__device__ __forceinline__ void mlp_layer(
    const unsigned short* __restrict__ Wm, const float* __restrict__ bm, int Rbias,
    const unsigned short* src, unsigned short* dst, unsigned short* __restrict__ Gg,
    int wave, int lane)
{
    const int quad = lane >> 4, l16 = lane & 15;
    const int rbw = wave * (I * 16);

    floatx4 acc[I][4];
    const floatx4 zero = {0.f, 0.f, 0.f, 0.f};
    #pragma unroll
    for (int i = 0; i < I; ++i)
        #pragma unroll
        for (int j = 0; j < 4; ++j) acc[i][j] = zero;

    #pragma unroll
    for (int kk = 0; kk < K / 32; ++kk) {
        short8 af[I], bf[4];
        #pragma unroll
        for (int i = 0; i < I; ++i)
            af[i] = *(const short8*)&Wm[(size_t)(rbw + i * 16 + l16) * K + kk * 32 + quad * 8];
        #pragma unroll
        for (int j = 0; j < 4; ++j) {
            const int cb = j * 16 + l16;
            bf[j] = *(const short8*)&src[cb * 256 + (((kk * 4 + quad) ^ (cb & 7)) * 8)];
        }
        #pragma unroll
        for (int i = 0; i < I; ++i)
            #pragma unroll
            for (int j = 0; j < 4; ++j)
                acc[i][j] = __builtin_amdgcn_mfma_f32_16x16x32_bf16(af[i], bf[j], acc[i][j], 0, 0, 0);
    }

    #pragma unroll
    for (int i = 0; i < I; ++i) {
        const int rb = rbw + i * 16 + quad * 4;
        float bv[4];
        #pragma unroll
        for (int rr = 0; rr < 4; ++rr)
            bv[rr] = (rb + rr < Rbias) ? bm[rb + rr] : 0.0f;
        #pragma unroll
        for (int j = 0; j < 4; ++j) {
            const int cb = j * 16 + l16;
            ushort4v o;
            #pragma unroll
            for (int rr = 0; rr < 4; ++rr)
                o[rr] = f2bf(sigm(acc[i][j][rr] + bv[rr]));
            if (!FINAL) {
                const int chunk = rb >> 3;
                *(ushort4v*)&dst[cb * 256 + ((chunk ^ (cb & 7)) * 8) + (rb & 7)] = o;
            } else if (rb < 68) {
                *(ushort4v*)&Gg[(size_t)cb * 4352 + rb] = o;
            }
        }
    }
}

// ---- fused MLP: all 5 layers, activations never leave LDS ----
// grid 1024 = 64 m x 16 batch-tiles (XCD-swizzled), 256 threads.
__global__ __launch_bounds__(256, 2)
void fused_mlp(const float* __restrict__ u,
               const unsigned short* __restrict__ w0_bf, const float* __restrict__ b0_,
               const unsigned short* __restrict__ w_bf,  const float* __restrict__ b_,
               const unsigned short* __restrict__ wf_bf, const float* __restrict__ bf_,
               unsigned short* __restrict__ Gflat) {
    __shared__ unsigned short Xa[64 * 256];
    __shared__ unsigned short Xb[64 * 256];

    const int bid = blockIdx.x;
    const int xcd = bid & 7, slot = bid >> 3;
    const int m  = (xcd << 3) + (slot >> 4);
    const int b0 = (slot & 15) << 6;
    const int tid = threadIdx.x, wave = tid >> 6, lane = tid & 63;

    // stage u (fp32) -> Xa (bf16, swizzled). 64 b x 64 d.
    {
        const int b = tid >> 2, dc = tid & 3;
        const float* up = u + (size_t)(b0 + b) * 64 + dc * 16;
        float4 v0 = *(const float4*)(up);
        float4 v1 = *(const float4*)(up + 4);
        float4 v2 = *(const float4*)(up + 8);
        float4 v3 = *(const float4*)(up + 12);
        short8 c0 = { (short)f2bf(v0.x), (short)f2bf(v0.y), (short)f2bf(v0.z), (short)f2bf(v0.w),
                      (short)f2bf(v1.x), (short)f2bf(v1.y), (short)f2bf(v1.z), (short)f2bf(v1.w) };
        short8 c1 = { (short)f2bf(v2.x), (short)f2bf(v2.y), (short)f2bf(v2.z), (short)f2bf(v2.w),
                      (short)f2bf(v3.x), (short)f2bf(v3.y), (short)f2bf(v3.z), (short)f2bf(v3.w) };
        *(short8*)&Xa[b * 256 + (((dc * 2)     ^ (b & 7)) * 8)] = c0;
        *(short8*)&Xa[b * 256 + (((dc * 2 + 1) ^ (b & 7)) * 8)] = c1;
    }
    __syncthreads();

    mlp_layer<64, 4, false>(w0_bf + (size_t)m * 256 * 64, b0_ + (size_t)m * 256, 256,
                            Xa, Xb, nullptr, wave, lane);
    __syncthreads();
    mlp_layer<256, 4, false>(w_bf + ((size_t)0 * 64 + m) * 65536, b_ + ((size_t)0 * 64 + m) * 256, 256,
                             Xb, Xa, nullptr, wave, lane);
    __syncthreads();
    mlp_layer<256, 4, false>(w_bf + ((size_t)1 * 64 + m) * 65536, b_ + ((size_t)1 * 64 + m) * 256, 256,
                             Xa, Xb, nullptr, wave, lane);
    __syncthreads();
    mlp_layer<256, 4, false>(w_bf + ((size_t)2 * 64 + m) * 65536, b_ + ((size_t)2 * 64 + m) * 256, 256,
                             Xb, Xa, nullptr, wave, lane);
    __syncthreads();
    mlp_layer<256, 2, true>(wf_bf + (size_t)m * 128 * 256, bf_ + (size_t)m * 65, 65,
                            Xa, nullptr, Gflat + (size_t)b0 * 4352 + m * 68, wave, lane);
}

// ---- contraction with K-split 4: P[kc][n][b] partials, fp32 ----
// grid 1024 (XCD-swizzled), 256 thr, 128x128 tile, K-chunk 1088.
__global__ __launch_bounds__(256, 2)
void contract_gemm(const unsigned short* __restrict__ XW,
                   const unsigned short* __restrict__ G,
                   float* __restrict__ P) {
    const int bid = blockIdx.x;
    const int xcd = bid & 7, slot = bid >> 3;          // 0..127
    const int kc  = slot >> 5;                          // 0..3
    const int rst = slot & 31;
    const int r0 = ((xcd << 2) + (rst >> 3)) << 7;      // n-tile
    const int c0 = (rst & 7) << 7;                      // b-tile
    const int kb = kc * 1088;
    float* Pc = P + (size_t)kc * 4096 * 1024;

    __shared__ unsigned short As[128 * 64];
    __shared__ unsigned short Bs[128 * 64];

    const int tid = threadIdx.x;
    const int wave = tid >> 6, lane = tid & 63;
    const int quad = lane >> 4, l16 = lane & 15;
    const int wr = (wave & 1) * 64;
    const int wc = (wave >> 1) * 64;
    const int srow = wave * 32 + (lane >> 3);
    const int spos = lane & 7;

    floatx4 acc[4][4];
    const floatx4 zero = {0.f, 0.f, 0.f, 0.f};
    #pragma unroll
    for (int i = 0; i < 4; ++i)
        #pragma unroll
        for (int j = 0; j < 4; ++j) acc[i][j] = zero;

    for (int k0 = kb; k0 < kb + 1088; k0 += BK) {
        #pragma unroll
        for (int t = 0; t < 4; ++t) {
            const int row = srow + t * 8;
            const int fc  = spos ^ (row & 7);
            load_lds16(XW + (size_t)(r0 + row) * 4352 + k0 + fc * 8,
                       &As[(wave * 32 + t * 8) * 64]);
            load_lds16(G + (size_t)(c0 + row) * 4352 + k0 + fc * 8,
                       &Bs[(wave * 32 + t * 8) * 64]);
        }
        __syncthreads();

        #pragma unroll
        for (int kk = 0; kk < 2; ++kk) {
            short8 af[4], bfr[4];
            #pragma unroll
            for (int i = 0; i < 4; ++i) {
                const int ra = wr + i * 16 + l16;
                af[i]  = *(const short8*)&As[ra * 64 + (((kk * 4 + quad) ^ (ra & 7)) * 8)];
                const int cb = wc + i * 16 + l16;
                bfr[i] = *(const short8*)&Bs[cb * 64 + (((kk * 4 + quad) ^ (cb & 7)) * 8)];
            }
            #pragma unroll
            for (int i = 0; i < 4; ++i)
                #pragma unroll
                for (int j = 0; j < 4; ++j)
                    acc[i][j] = __builtin_amdgcn_mfma_f32_16x16x32_bf16(af[i], bfr[j], acc[i][j], 0, 0, 0);
        }
        __syncthreads();
    }

    #pragma unroll
    for (int i = 0; i < 4; ++i) {
        const int rb = r0 + wr + i * 16 + quad * 4;
        #pragma unroll
        for (int rr = 0; rr < 4; ++rr)
            #pragma unroll
            for (int j = 0; j < 4; ++j) {
                const int col = c0 + wc + j * 16 + l16;
                Pc[(size_t)(rb + rr) * 1024 + col] = acc[i][j][rr];
            }
    }
}

// ---- final reduce of 4 K-partials ----
__global__ void reduce4(const float* __restrict__ P, float* __restrict__ out) {
    const int i = blockIdx.x * 256 + threadIdx.x;    // per float4, 1048576 total
    const float4* p = (const float4*)P;
    float4 a = p[i], b = p[i + 1048576], c = p[i + 2097152], d = p[i + 3145728];
    float4 o = { a.x + b.x + c.x + d.x, a.y + b.y + c.y + d.y,
                 a.z + b.z + c.z + d.z, a.w + b.w + c.w + d.w };
    ((float4*)out)[i] = o;
}

extern "C" void kernel_launch(void* const* d_in, const int* in_sizes, int n_in,
                              void* d_out, int out_size, void* d_ws, size_t ws_size,
                              hipStream_t stream) {
    const float* u   = (const float*)d_in[0];
    const float* w0  = (const float*)d_in[1];
    const float* b0_ = (const float*)d_in[2];
    const float* w   = (const float*)d_in[3];
    const float* b   = (const float*)d_in[4];
    const float* wf  = (const float*)d_in[5];
    const float* bf_ = (const float*)d_in[6];
    const float* xi  = (const float*)d_in[7];
    float* out = (float*)d_out;

    unsigned short* w0_bf = (unsigned short*)d_ws;             // 1,048,576
    unsigned short* w_bf  = w0_bf + 1048576;                   // 12,582,912
    unsigned short* wf_bf = w_bf  + 12582912;                  // 2,097,152
    unsigned short* Gflat = wf_bf + 2097152;                   // 4,456,448 (1024 x 4352)
    unsigned short* XW    = Gflat + 4456448;                   // 17,825,792 (4096 x 4352)
    float*          P     = (float*)(XW + 17825792);           // 4 x 4096 x 1024 fp32

    cvt_all<<<15360, 256, 0, stream>>>(w0, w, wf, w0_bf, w_bf, wf_bf);
    build_xw<<<dim3(32, 64), 256, 0, stream>>>(xi, (unsigned int*)XW);
    fused_mlp<<<1024, 256, 0, stream>>>(u, w0_bf, b0_, w_bf, b, wf_bf, bf_, Gflat);
    contract_gemm<<<1024, 256, 0, stream>>>(XW, Gflat, P);
    reduce4<<<4096, 256, 0, stream>>>(P, out);
}